// Round 6
// baseline (722.256 us; speedup 1.0000x reference)
//
#include <hip/hip_runtime.h>
#include <hip/hip_bf16.h>
#include <stdint.h>

#define B_   16
#define CIN_ 32
#define S_   512
#define D_   256
#define H_   8
#define L_   4
#define FF_  1024
#define HD_  32
#define EPS_ 1e-5f

typedef __hip_bfloat16 bf16;
typedef __attribute__((ext_vector_type(8))) short short8;
typedef __attribute__((ext_vector_type(4))) float floatx4;

__device__ __forceinline__ float b2f(bf16 v) { return __bfloat162float(v); }
__device__ __forceinline__ bf16 f2b(float v) { return __float2bfloat16(v); }
__device__ __forceinline__ float gelu_f(float v) {
    return 0.5f * v * (1.0f + erff(v * 0.70710678118654752f));
}
__device__ __forceinline__ float pe_val(int s, int d) {
    int m2 = d & ~1;
    float div = expf((float)m2 * (-9.210340371976184f / 256.0f));
    float ang = (float)s * div * 0.5f;  // scale = D/S = 0.5
    return (d & 1) ? cosf(ang) : sinf(ang);
}

// ---------------- weight transpose-cast: dst[n][k] = src[k][n] --------------
__global__ void wtrans_kernel(const float* __restrict__ src, bf16* __restrict__ dst,
                              int K, int N, long lss, long lds_, int rowoff) {
    __shared__ float tile[32][33];
    int l = blockIdx.z;
    int n0 = blockIdx.x * 32, k0 = blockIdx.y * 32;
    int tx = threadIdx.x & 31, ty0 = threadIdx.x >> 5;
#pragma unroll
    for (int r = 0; r < 4; ++r) {
        int ky = r * 8 + ty0;
        tile[ky][tx] = src[l * lss + (long)(k0 + ky) * N + n0 + tx];
    }
    __syncthreads();
#pragma unroll
    for (int r = 0; r < 4; ++r) {
        int ny = r * 8 + ty0;
        dst[l * lds_ + (long)(rowoff + n0 + ny) * K + k0 + tx] = f2b(tile[tx][ny]);
    }
}

// ---------------- conv weight prep (fold BN scale) + shift vectors ----------
__global__ void convprep_kernel(const float* __restrict__ w1c, const float* __restrict__ cb1,
                                const float* __restrict__ g1, const float* __restrict__ bb1,
                                const float* __restrict__ w2c, const float* __restrict__ cb2,
                                const float* __restrict__ g2, const float* __restrict__ bb2,
                                bf16* __restrict__ c1w, bf16* __restrict__ c2w,
                                float* __restrict__ sh1, float* __restrict__ sh2) {
    int bid = blockIdx.x;
    int ty = threadIdx.x >> 4, t16 = threadIdx.x & 15;
    float rinv = rsqrtf(1.0f + EPS_);
    if (bid < 16) {
        int o = bid * 16 + ty;
        float scale = g1[o] * rinv;
        if (t16 == 0) sh1[o] = cb1[o] * scale + bb1[o];
        for (int j = t16; j < 256; j += 16) {
            int kk = j >> 5, i = j & 31;
            float v = (kk < 7) ? w1c[o * 224 + i * 7 + kk] * scale : 0.0f;
            c1w[o * 256 + kk * 32 + i] = f2b(v);
        }
    } else {
        int o = (bid - 16) * 16 + ty;
        float scale = g2[o] * rinv;
        if (t16 == 0) sh2[o] = cb2[o] * scale + bb2[o];
        for (int j = t16; j < D_ * 5; j += 16) {
            int i = j / 5, kk = j % 5;
            c2w[o * 1280 + kk * 256 + i] = f2b(w2c[o * 1280 + i * 5 + kk] * scale);
        }
    }
}

// ---------------- im2col for conv1: x (B,CIN,S) f32 -> col (B*S, 256) bf16 --
__global__ void im2col1_kernel(const float* __restrict__ x, bf16* __restrict__ col) {
    int kk = blockIdx.x, b = blockIdx.y;  // kk 0..7, kk==7 -> zero pad
    for (int t = threadIdx.x; t < 512 * 32; t += 256) {
        int s = t & 511, i = t >> 9;
        int sp = s + kk - 3;
        float v = (kk < 7 && sp >= 0 && sp < 512) ? x[((b << 5) + i) * 512 + sp] : 0.0f;
        col[(long)((b << 9) + s) * 256 + kk * 32 + i] = f2b(v);
    }
}

// ---------------- im2col for conv2: h1 (B*S, 256) bf16 -> col (B*S, 1280) ---
__global__ void im2col2_kernel(const bf16* __restrict__ h1, bf16* __restrict__ col) {
    int kk = blockIdx.x, b = blockIdx.y;
    for (int t = threadIdx.x; t < 512 * 32; t += 256) {
        int c = t & 31, s = t >> 5;
        int sp = s + kk - 2;
        uint4 v = {0u, 0u, 0u, 0u};
        if (sp >= 0 && sp < 512)
            v = *(const uint4*)((const char*)h1 + ((long)((b << 9) + sp) * 256 + c * 8) * 2);
        *(uint4*)((char*)col + ((long)((b << 9) + s) * 1280 + kk * 256 + c * 8) * 2) = v;
    }
}

// ---------------- layernorm (D=256): t f32 -> bf16 or f32 -------------------
template <bool OUT_BF16>
__global__ void ln_kernel(const float* __restrict__ x, const float* __restrict__ g,
                          const float* __restrict__ bt, float* __restrict__ out_f,
                          bf16* __restrict__ out_b) {
    int row = blockIdx.x;
    int tid = threadIdx.x;  // 256 == D
    float v = x[(long)row * D_ + tid];
    float s1 = v, s2 = v * v;
    __shared__ float red[8];
#pragma unroll
    for (int off = 32; off; off >>= 1) {
        s1 += __shfl_xor(s1, off);
        s2 += __shfl_xor(s2, off);
    }
    int wave = tid >> 6;
    if ((tid & 63) == 0) { red[wave] = s1; red[4 + wave] = s2; }
    __syncthreads();
    if (tid == 0) {
        float a = red[0] + red[1] + red[2] + red[3];
        float q = red[4] + red[5] + red[6] + red[7];
        float mu = a * (1.0f / D_);
        float var = q * (1.0f / D_) - mu * mu;
        red[0] = mu;
        red[1] = rsqrtf(var + EPS_);
    }
    __syncthreads();
    float y = (v - red[0]) * red[1] * g[tid] + bt[tid];
    if (OUT_BF16) out_b[(long)row * D_ + tid] = f2b(y);
    else          out_f[(long)row * D_ + tid] = y;
}

// ------- swizzled async staging: ROWS x 128B tile, 16B chunk XOR swizzle ----
template <int ROWS>
__device__ __forceinline__ void stage_sw(const char* gbase, long rs_bytes, int k_byte_off,
                                         char* lds_base, int tid) {
    constexpr int ROUNDS = ROWS / 32;
    char* lp = lds_base + (tid & 192) * 16;  // wave-uniform base
#pragma unroll
    for (int r = 0; r < ROUNDS; ++r) {
        int s = r * 256 + tid;
        int row = s >> 3;
        int q = ((s & 7) ^ (row & 7)) * 16;
        const char* gp = gbase + (long)row * rs_bytes + k_byte_off + q;
        __builtin_amdgcn_global_load_lds((const __attribute__((address_space(1))) void*)gp,
                                         (__attribute__((address_space(3))) void*)(lp + r * 4096),
                                         16, 0, 0);
    }
}
__device__ __forceinline__ int sw_off(int m, int qc) {
    return m * 128 + ((qc ^ (m & 7)) * 16);
}

// ------- bf16 MFMA GEMM, BMxBN tile, BK=64, double-buffered -----------------
enum { FB = 1, FG = 2, FR = 4, FO16 = 8, FPE = 16 };

// VT: N==768 QKV mode -> cols [0,512) to outb (row stride 512), cols [512,768)
// transposed into vt (B*H,32,512).
template <int BM, int BN, int WM, int WN, int FLAGS, bool VT>
__global__ __launch_bounds__(256) void gemm128(const bf16* __restrict__ A, const bf16* __restrict__ Wt,
                                               const float* __restrict__ bias, const float* __restrict__ res,
                                               float* __restrict__ outf, bf16* __restrict__ outb,
                                               bf16* __restrict__ vt, int M, int N, int K) {
    constexpr int WAVES_M = BM / WM;
    constexpr int FM = WM / 16, FN = WN / 16;
    __shared__ __align__(16) short As[2][BM * 64];
    __shared__ __align__(16) short Bs[2][BN * 64];
    int tid = threadIdx.x;
    int wave = tid >> 6, lane = tid & 63;
    int frow = lane & 15, fquad = lane >> 4;
    int m0 = blockIdx.y * BM, n0 = blockIdx.x * BN;
    int wm = (wave % WAVES_M) * WM, wn = (wave / WAVES_M) * WN;
    floatx4 acc[FM][FN] = {};
    const char* Ab = (const char*)A + (long)m0 * K * 2;
    const char* Bb = (const char*)Wt + (long)n0 * K * 2;
    long rs = (long)K * 2;
    int KT = K >> 6;
    stage_sw<BM>(Ab, rs, 0, (char*)As[0], tid);
    stage_sw<BN>(Bb, rs, 0, (char*)Bs[0], tid);
    for (int kt = 0; kt < KT; ++kt) {
        int cur = kt & 1;
        __syncthreads();
        if (kt + 1 < KT) {
            stage_sw<BM>(Ab, rs, (kt + 1) * 128, (char*)As[1 - cur], tid);
            stage_sw<BN>(Bb, rs, (kt + 1) * 128, (char*)Bs[1 - cur], tid);
        }
        const char* Ap = (const char*)As[cur];
        const char* Bp = (const char*)Bs[cur];
#pragma unroll
        for (int kh = 0; kh < 2; ++kh) {
            short8 af[FM], bw[FN];
#pragma unroll
            for (int i = 0; i < FM; ++i)
                af[i] = *(const short8*)(Ap + sw_off(wm + i * 16 + frow, kh * 4 + fquad));
#pragma unroll
            for (int j = 0; j < FN; ++j)
                bw[j] = *(const short8*)(Bp + sw_off(wn + j * 16 + frow, kh * 4 + fquad));
#pragma unroll
            for (int i = 0; i < FM; ++i)
#pragma unroll
                for (int j = 0; j < FN; ++j)
                    acc[i][j] = __builtin_amdgcn_mfma_f32_16x16x32_bf16(af[i], bw[j], acc[i][j], 0, 0, 0);
        }
    }
#pragma unroll
    for (int i = 0; i < FM; ++i) {
#pragma unroll
        for (int j = 0; j < FN; ++j) {
#pragma unroll
            for (int r = 0; r < 4; ++r) {
                int row = m0 + wm + i * 16 + fquad * 4 + r;
                int col = n0 + wn + j * 16 + frow;
                float v = acc[i][j][r];
                if (FLAGS & FB) v += bias[col];
                if (FLAGS & FG) v = gelu_f(v);
                if (FLAGS & FPE) v += pe_val(row & 511, col);
                if (FLAGS & FR) v += res[(long)row * N + col];
                if (VT) {
                    if (col < 512) {
                        outb[(long)row * 512 + col] = f2b(v);
                    } else {
                        int h = (col - 512) >> 5, d = col & 31;
                        int b = row >> 9, s = row & 511;
                        vt[(long)((b * 8 + h) * 32 + d) * 512 + s] = f2b(v);
                    }
                } else if (FLAGS & FO16) {
                    outb[(long)row * N + col] = f2b(v);
                } else {
                    outf[(long)row * N + col] = v;
                }
            }
        }
    }
}

// ---------------- fused flash attention (MFMA) ------------------------------
// qk (M,512) bf16: Q cols 0-255, K cols 256-511. Vt (B*H,32,512) bf16.
#define PSTR 136
__global__ __launch_bounds__(256) void fattn_kernel(const bf16* __restrict__ qk,
                                                    const bf16* __restrict__ Vt,
                                                    const float* __restrict__ bias_l,
                                                    bf16* __restrict__ ctx) {
    __shared__ __align__(16) short Ks[128 * 32];
    __shared__ __align__(16) short Vs[32 * 128];
    __shared__ __align__(16) short Ps[4 * 32 * PSTR];
    __shared__ float bias_s[640];
    int tid = threadIdx.x;
    int wave = tid >> 6, lane = tid & 63;
    int frow = lane & 15, fquad = lane >> 4;
    int bh = blockIdx.y;
    int b = bh >> 3, h = bh & 7;
    int i0 = blockIdx.x * 128;
    int wm = wave * 32;
    const float scale = 0.17677669529663687f;

    for (int t = tid; t < 639; t += 256) bias_s[t] = bias_l[(i0 + t) * 8 + h];

    short8 qf[2];
#pragma unroll
    for (int i = 0; i < 2; ++i)
        qf[i] = *(const short8*)((const short*)qk +
                 (long)((b << 9) + i0 + wm + i * 16 + frow) * 512 + h * 32 + fquad * 8);

    const char* gK = (const char*)qk + (long)b * 512 * 1024 + 512 + h * 64;
    const char* gV = (const char*)Vt + (long)bh * 32 * 1024;

    floatx4 acc_o[2][2] = {};
    float run_m[2][4], run_l[2][4];
#pragma unroll
    for (int i = 0; i < 2; ++i)
#pragma unroll
        for (int r = 0; r < 4; ++r) { run_m[i][r] = -1e30f; run_l[i][r] = 0.0f; }

    short* Pw = Ps + wave * 32 * PSTR;
    bf16* Pb = (bf16*)Pw;

    for (int j0 = 0; j0 < 512; j0 += 128) {
        {
            char* lpK = (char*)Ks + (tid & 192) * 16;
            char* lpV = (char*)Vs + (tid & 192) * 16;
#pragma unroll
            for (int r = 0; r < 2; ++r) {
                int off = r * 4096 + tid * 16;
                const char* gp = gK + (long)(j0 + (off >> 6)) * 1024 + (off & 63);
                __builtin_amdgcn_global_load_lds((const __attribute__((address_space(1))) void*)gp,
                                                 (__attribute__((address_space(3))) void*)(lpK + r * 4096), 16, 0, 0);
            }
#pragma unroll
            for (int r = 0; r < 2; ++r) {
                int off = r * 4096 + tid * 16;
                const char* gp = gV + (long)(off >> 8) * 1024 + j0 * 2 + (off & 255);
                __builtin_amdgcn_global_load_lds((const __attribute__((address_space(1))) void*)gp,
                                                 (__attribute__((address_space(3))) void*)(lpV + r * 4096), 16, 0, 0);
            }
        }
        __syncthreads();

        floatx4 accs[2][8] = {};
#pragma unroll
        for (int jt = 0; jt < 8; ++jt) {
            short8 bk = *(const short8*)(Ks + (jt * 16 + frow) * 32 + fquad * 8);
#pragma unroll
            for (int i = 0; i < 2; ++i)
                accs[i][jt] = __builtin_amdgcn_mfma_f32_16x16x32_bf16(qf[i], bk, accs[i][jt], 0, 0, 0);
        }
#pragma unroll
        for (int i = 0; i < 2; ++i) {
            int irel = wm + i * 16 + fquad * 4;
#pragma unroll
            for (int jt = 0; jt < 8; ++jt) {
                int jl = j0 + jt * 16 + frow;
#pragma unroll
                for (int r = 0; r < 4; ++r)
                    accs[i][jt][r] = accs[i][jt][r] * scale + bias_s[irel + r + 511 - jl];
            }
        }
#pragma unroll
        for (int i = 0; i < 2; ++i) {
#pragma unroll
            for (int r = 0; r < 4; ++r) {
                float m = -1e30f;
#pragma unroll
                for (int jt = 0; jt < 8; ++jt) m = fmaxf(m, accs[i][jt][r]);
                m = fmaxf(m, __shfl_xor(m, 1));
                m = fmaxf(m, __shfl_xor(m, 2));
                m = fmaxf(m, __shfl_xor(m, 4));
                m = fmaxf(m, __shfl_xor(m, 8));
                float nm = fmaxf(run_m[i][r], m);
                float al = __expf(run_m[i][r] - nm);
                run_m[i][r] = nm;
                float ts = 0.0f;
#pragma unroll
                for (int jt = 0; jt < 8; ++jt) {
                    float p = __expf(accs[i][jt][r] - nm);
                    accs[i][jt][r] = p;
                    ts += p;
                }
                ts += __shfl_xor(ts, 1);
                ts += __shfl_xor(ts, 2);
                ts += __shfl_xor(ts, 4);
                ts += __shfl_xor(ts, 8);
                run_l[i][r] = run_l[i][r] * al + ts;
                acc_o[i][0][r] *= al;
                acc_o[i][1][r] *= al;
            }
        }
#pragma unroll
        for (int i = 0; i < 2; ++i)
#pragma unroll
            for (int jt = 0; jt < 8; ++jt)
#pragma unroll
                for (int r = 0; r < 4; ++r)
                    Pb[(i * 16 + fquad * 4 + r) * PSTR + jt * 16 + frow] = f2b(accs[i][jt][r]);
#pragma unroll
        for (int ks = 0; ks < 4; ++ks) {
            short8 ap[2], bv[2];
#pragma unroll
            for (int i = 0; i < 2; ++i)
                ap[i] = *(const short8*)(Pw + (i * 16 + frow) * PSTR + ks * 32 + fquad * 8);
#pragma unroll
            for (int dt = 0; dt < 2; ++dt)
                bv[dt] = *(const short8*)(Vs + (dt * 16 + frow) * 128 + ks * 32 + fquad * 8);
#pragma unroll
            for (int i = 0; i < 2; ++i)
#pragma unroll
                for (int dt = 0; dt < 2; ++dt)
                    acc_o[i][dt] = __builtin_amdgcn_mfma_f32_16x16x32_bf16(ap[i], bv[dt], acc_o[i][dt], 0, 0, 0);
        }
        __syncthreads();
    }

#pragma unroll
    for (int i = 0; i < 2; ++i) {
#pragma unroll
        for (int r = 0; r < 4; ++r) {
            float inv = 1.0f / run_l[i][r];
            int row = i0 + wm + i * 16 + fquad * 4 + r;
#pragma unroll
            for (int dt = 0; dt < 2; ++dt) {
                int d = dt * 16 + frow;
                ctx[(long)((b << 9) + row) * 256 + h * 32 + d] = f2b(acc_o[i][dt][r] * inv);
            }
        }
    }
}

extern "C" void kernel_launch(void* const* d_in, const int* in_sizes, int n_in,
                              void* d_out, int out_size, void* d_ws, size_t ws_size,
                              hipStream_t stream) {
    const float* x        = (const float*)d_in[0];
    const float* conv1_w  = (const float*)d_in[1];
    const float* conv1_b  = (const float*)d_in[2];
    const float* bn1_g    = (const float*)d_in[3];
    const float* bn1_b    = (const float*)d_in[4];
    const float* conv2_w  = (const float*)d_in[5];
    const float* conv2_b  = (const float*)d_in[6];
    const float* bn2_g    = (const float*)d_in[7];
    const float* bn2_b    = (const float*)d_in[8];
    const float* ln1_g    = (const float*)d_in[9];
    const float* ln1_b    = (const float*)d_in[10];
    const float* wq       = (const float*)d_in[11];
    const float* wk       = (const float*)d_in[12];
    const float* wv       = (const float*)d_in[13];
    const float* wo       = (const float*)d_in[14];
    const float* bo       = (const float*)d_in[15];
    const float* bias_tab = (const float*)d_in[16];
    const float* ln2_g    = (const float*)d_in[17];
    const float* ln2_b    = (const float*)d_in[18];
    const float* w1       = (const float*)d_in[19];
    const float* b1       = (const float*)d_in[20];
    const float* w2       = (const float*)d_in[21];
    const float* b2       = (const float*)d_in[22];
    const float* fn_g     = (const float*)d_in[23];
    const float* fn_b     = (const float*)d_in[24];
    (void)in_sizes; (void)n_in; (void)out_size; (void)ws_size;

    const int M = B_ * S_;  // 8192
    char* wsb = (char*)d_ws;
    float* t    = (float*)wsb;                          // [0, 8M)
    bf16* qk    = (bf16*)(wsb + (8u << 20));            // [8M, 16M)  Q|K (M,512)
    bf16* h1    = (bf16*)(wsb + (8u << 20));            // alias (4 MB, dead before qk)
    char* reg2  = wsb + (16u << 20);                    // [16M, 36M)
    bf16* Vt    = (bf16*)reg2;                          // 8 MB  (qkv-gemm -> fattn)
    bf16* ff1   = (bf16*)reg2;                          // 16 MB (ff1-gemm -> ff2-gemm)
    bf16* col1  = (bf16*)reg2;                          // alias (tokenizer, 4 MB)
    bf16* col2  = (bf16*)reg2;                          // alias (tokenizer, 20 MB)
    bf16* xnctx = (bf16*)(reg2 + (20u << 20));          // 4 MB (xn and ctx)
    bf16* wqkvT = (bf16*)(wsb + (40u << 20));           // L*768*256
    bf16* woT   = wqkvT + (long)L_ * 768 * 256;         // L*256*256
    bf16* w1T   = woT + (long)L_ * 256 * 256;           // L*1024*256
    bf16* w2T   = w1T + (long)L_ * 1024 * 256;          // L*256*1024
    bf16* c1w   = w2T + (long)L_ * 256 * 1024;          // 256*256 (padded K)
    bf16* c2w   = c1w + 256 * 256;                      // 256*1280
    float* sh1  = (float*)(c2w + 256 * 1280);           // 256
    float* sh2  = sh1 + 256;                            // 256

    // ---- weight prep ----
    wtrans_kernel<<<dim3(8, 8, L_), 256, 0, stream>>>(wq, wqkvT, 256, 256, 65536, 768 * 256, 0);
    wtrans_kernel<<<dim3(8, 8, L_), 256, 0, stream>>>(wk, wqkvT, 256, 256, 65536, 768 * 256, 256);
    wtrans_kernel<<<dim3(8, 8, L_), 256, 0, stream>>>(wv, wqkvT, 256, 256, 65536, 768 * 256, 512);
    wtrans_kernel<<<dim3(8, 8, L_), 256, 0, stream>>>(wo, woT, 256, 256, 65536, 65536, 0);
    wtrans_kernel<<<dim3(32, 8, L_), 256, 0, stream>>>(w1, w1T, 256, 1024, 262144, 262144, 0);
    wtrans_kernel<<<dim3(8, 32, L_), 256, 0, stream>>>(w2, w2T, 1024, 256, 262144, 262144, 0);
    convprep_kernel<<<32, 256, 0, stream>>>(conv1_w, conv1_b, bn1_g, bn1_b,
                                            conv2_w, conv2_b, bn2_g, bn2_b,
                                            c1w, c2w, sh1, sh2);

    // ---- tokenizer ----
    im2col1_kernel<<<dim3(8, B_), 256, 0, stream>>>(x, col1);
    gemm128<128, 64, 32, 64, FB | FG | FO16, false><<<dim3(4, 64), 256, 0, stream>>>(
        col1, c1w, sh1, nullptr, nullptr, h1, nullptr, M, 256, 256);
    im2col2_kernel<<<dim3(5, B_), 256, 0, stream>>>(h1, col2);
    gemm128<128, 64, 32, 64, FB | FG | FPE, false><<<dim3(4, 64), 256, 0, stream>>>(
        col2, c2w, sh2, nullptr, t, nullptr, nullptr, M, 256, 1280);

    // ---- transformer layers ----
    for (int l = 0; l < L_; ++l) {
        ln_kernel<true><<<M, 256, 0, stream>>>(t, ln1_g + l * D_, ln1_b + l * D_, nullptr, xnctx);
        gemm128<128, 128, 64, 64, FO16, true><<<dim3(6, 64), 256, 0, stream>>>(
            xnctx, wqkvT + (long)l * 768 * 256, nullptr, nullptr, nullptr, qk, Vt, M, 768, 256);
        fattn_kernel<<<dim3(4, B_ * H_), 256, 0, stream>>>(
            qk, Vt, bias_tab + (long)l * (2 * S_ - 1) * H_, xnctx);
        gemm128<128, 64, 32, 64, FB | FR, false><<<dim3(4, 64), 256, 0, stream>>>(
            xnctx, woT + (long)l * 65536, bo + l * D_, t, t, nullptr, nullptr, M, 256, 256);
        ln_kernel<true><<<M, 256, 0, stream>>>(t, ln2_g + l * D_, ln2_b + l * D_, nullptr, xnctx);
        gemm128<128, 128, 64, 64, FB | FG | FO16, false><<<dim3(8, 64), 256, 0, stream>>>(
            xnctx, w1T + (long)l * 262144, b1 + l * FF_, nullptr, nullptr, ff1, nullptr, M, 1024, 256);
        gemm128<128, 64, 32, 64, FB | FR, false><<<dim3(4, 64), 256, 0, stream>>>(
            ff1, w2T + (long)l * 262144, b2 + l * D_, t, t, nullptr, nullptr, M, 256, 1024);
    }
    ln_kernel<false><<<M, 256, 0, stream>>>(t, fn_g, fn_b, (float*)d_out, nullptr);
}

// Round 7
// 606.691 us; speedup vs baseline: 1.1905x; 1.1905x over previous
//
#include <hip/hip_runtime.h>
#include <hip/hip_bf16.h>
#include <stdint.h>

#define B_   16
#define CIN_ 32
#define S_   512
#define D_   256
#define H_   8
#define L_   4
#define FF_  1024
#define HD_  32
#define EPS_ 1e-5f

typedef __hip_bfloat16 bf16;
typedef __attribute__((ext_vector_type(8))) short short8;
typedef __attribute__((ext_vector_type(4))) float floatx4;

__device__ __forceinline__ float b2f(bf16 v) { return __bfloat162float(v); }
__device__ __forceinline__ bf16 f2b(float v) { return __float2bfloat16(v); }
__device__ __forceinline__ float gelu_f(float v) {
    return 0.5f * v * (1.0f + erff(v * 0.70710678118654752f));
}
__device__ __forceinline__ float pe_val(int s, int d) {
    int m2 = d & ~1;
    float div = expf((float)m2 * (-9.210340371976184f / 256.0f));
    float ang = (float)s * div * 0.5f;  // scale = D/S = 0.5
    return (d & 1) ? cosf(ang) : sinf(ang);
}

// ---------------- mega prep: 6 wtrans jobs + convprep in one launch ---------
// blocks [0, 3072): weight transpose tiles; [3072, 3104): conv weight prep
__device__ __forceinline__ void wtrans_tile(const float* __restrict__ src, bf16* __restrict__ dst,
                                            int K, int N, int n0, int k0, int rowoff,
                                            float (*tile)[33], int tid) {
    int tx = tid & 31, ty0 = tid >> 5;
#pragma unroll
    for (int r = 0; r < 4; ++r) {
        int ky = r * 8 + ty0;
        tile[ky][tx] = src[(long)(k0 + ky) * N + n0 + tx];
    }
    __syncthreads();
#pragma unroll
    for (int r = 0; r < 4; ++r) {
        int ny = r * 8 + ty0;
        dst[(long)(rowoff + n0 + ny) * K + k0 + tx] = f2b(tile[tx][ny]);
    }
}

__global__ void prep_kernel(const float* __restrict__ wq, const float* __restrict__ wk,
                            const float* __restrict__ wv, const float* __restrict__ wo,
                            const float* __restrict__ w1, const float* __restrict__ w2,
                            bf16* __restrict__ wqkvT, bf16* __restrict__ woT,
                            bf16* __restrict__ w1T, bf16* __restrict__ w2T,
                            const float* __restrict__ w1c, const float* __restrict__ cb1,
                            const float* __restrict__ g1, const float* __restrict__ bb1,
                            const float* __restrict__ w2c, const float* __restrict__ cb2,
                            const float* __restrict__ g2, const float* __restrict__ bb2,
                            bf16* __restrict__ c1w, bf16* __restrict__ c2w,
                            float* __restrict__ sh1, float* __restrict__ sh2) {
    __shared__ float tile[32][33];
    int tid = threadIdx.x;
    int bid = blockIdx.x;
    if (bid < 3072) {
        int l = bid / 768, r = bid % 768;
        if (r < 256) {
            int which = r >> 6, rr = r & 63;
            int n0 = (rr & 7) * 32, k0 = (rr >> 3) * 32;
            const float* s = (which == 0 ? wq : which == 1 ? wk : which == 2 ? wv : wo) + (long)l * 65536;
            bf16* d = (which == 3) ? (woT + (long)l * 65536) : (wqkvT + (long)l * 768 * 256);
            wtrans_tile(s, d, 256, 256, n0, k0, (which == 3) ? 0 : which * 256, tile, tid);
        } else if (r < 512) {
            int rr = r - 256;
            int n0 = (rr & 31) * 32, k0 = (rr >> 5) * 32;
            wtrans_tile(w1 + (long)l * 262144, w1T + (long)l * 262144, 256, 1024, n0, k0, 0, tile, tid);
        } else {
            int rr = r - 512;
            int n0 = (rr & 7) * 32, k0 = (rr >> 3) * 32;
            wtrans_tile(w2 + (long)l * 262144, w2T + (long)l * 262144, 1024, 256, n0, k0, 0, tile, tid);
        }
        return;
    }
    int cb = bid - 3072;
    int ty = tid >> 4, t16 = tid & 15;
    float rinv = rsqrtf(1.0f + EPS_);
    if (cb < 16) {
        int o = cb * 16 + ty;
        float scale = g1[o] * rinv;
        if (t16 == 0) sh1[o] = cb1[o] * scale + bb1[o];
        for (int j = t16; j < 256; j += 16) {
            int kk = j >> 5, i = j & 31;
            float v = (kk < 7) ? w1c[o * 224 + i * 7 + kk] * scale : 0.0f;
            c1w[o * 256 + kk * 32 + i] = f2b(v);
        }
    } else {
        int o = (cb - 16) * 16 + ty;
        float scale = g2[o] * rinv;
        if (t16 == 0) sh2[o] = cb2[o] * scale + bb2[o];
        for (int j = t16; j < D_ * 5; j += 16) {
            int i = j / 5, kk = j % 5;
            c2w[o * 1280 + kk * 256 + i] = f2b(w2c[o * 1280 + i * 5 + kk] * scale);
        }
    }
}

// ---------------- im2col for conv1: x (B,CIN,S) f32 -> col (B*S, 256) bf16 --
__global__ void im2col1_kernel(const float* __restrict__ x, bf16* __restrict__ col) {
    int kk = blockIdx.x, b = blockIdx.y;  // kk 0..7, kk==7 -> zero pad
    for (int t = threadIdx.x; t < 512 * 32; t += 256) {
        int s = t & 511, i = t >> 9;
        int sp = s + kk - 3;
        float v = (kk < 7 && sp >= 0 && sp < 512) ? x[((b << 5) + i) * 512 + sp] : 0.0f;
        col[(long)((b << 9) + s) * 256 + kk * 32 + i] = f2b(v);
    }
}

// ---------------- im2col for conv2: h1 (B*S, 256) bf16 -> col (B*S, 1280) ---
__global__ void im2col2_kernel(const bf16* __restrict__ h1, bf16* __restrict__ col) {
    int kk = blockIdx.x, b = blockIdx.y;
    for (int t = threadIdx.x; t < 512 * 32; t += 256) {
        int c = t & 31, s = t >> 5;
        int sp = s + kk - 2;
        uint4 v = {0u, 0u, 0u, 0u};
        if (sp >= 0 && sp < 512)
            v = *(const uint4*)((const char*)h1 + ((long)((b << 9) + sp) * 256 + c * 8) * 2);
        *(uint4*)((char*)col + ((long)((b << 9) + s) * 1280 + kk * 256 + c * 8) * 2) = v;
    }
}

// ---------------- layernorm (D=256): t f32 -> bf16 or f32 -------------------
template <bool OUT_BF16>
__global__ void ln_kernel(const float* __restrict__ x, const float* __restrict__ g,
                          const float* __restrict__ bt, float* __restrict__ out_f,
                          bf16* __restrict__ out_b) {
    int row = blockIdx.x;
    int tid = threadIdx.x;  // 256 == D
    float v = x[(long)row * D_ + tid];
    float s1 = v, s2 = v * v;
    __shared__ float red[8];
#pragma unroll
    for (int off = 32; off; off >>= 1) {
        s1 += __shfl_xor(s1, off);
        s2 += __shfl_xor(s2, off);
    }
    int wave = tid >> 6;
    if ((tid & 63) == 0) { red[wave] = s1; red[4 + wave] = s2; }
    __syncthreads();
    if (tid == 0) {
        float a = red[0] + red[1] + red[2] + red[3];
        float q = red[4] + red[5] + red[6] + red[7];
        float mu = a * (1.0f / D_);
        float var = q * (1.0f / D_) - mu * mu;
        red[0] = mu;
        red[1] = rsqrtf(var + EPS_);
    }
    __syncthreads();
    float y = (v - red[0]) * red[1] * g[tid] + bt[tid];
    if (OUT_BF16) out_b[(long)row * D_ + tid] = f2b(y);
    else          out_f[(long)row * D_ + tid] = y;
}

// ------- swizzled async staging: ROWS x 128B tile, 16B chunk XOR swizzle ----
template <int ROWS>
__device__ __forceinline__ void stage_sw(const char* gbase, long rs_bytes, int k_byte_off,
                                         char* lds_base, int tid) {
    constexpr int ROUNDS = ROWS / 32;
    char* lp = lds_base + (tid & 192) * 16;  // wave-uniform base
#pragma unroll
    for (int r = 0; r < ROUNDS; ++r) {
        int s = r * 256 + tid;
        int row = s >> 3;
        int q = ((s & 7) ^ (row & 7)) * 16;
        const char* gp = gbase + (long)row * rs_bytes + k_byte_off + q;
        __builtin_amdgcn_global_load_lds((const __attribute__((address_space(1))) void*)gp,
                                         (__attribute__((address_space(3))) void*)(lp + r * 4096),
                                         16, 0, 0);
    }
}
__device__ __forceinline__ int sw_off(int m, int qc) {
    return m * 128 + ((qc ^ (m & 7)) * 16);
}

// ------- bf16 MFMA GEMM, 64x64 tile, BK=64, dbuf, XCD-swizzled grid ---------
// grid.x = (M/64)*NB; decode keeps all n-blocks of an m-band on one XCD.
enum { FB = 1, FG = 2, FR = 4, FO16 = 8, FPE = 16 };

template <int NB, int FLAGS, bool VT>
__global__ __launch_bounds__(256) void gemm_sw(const bf16* __restrict__ A, const bf16* __restrict__ Wt,
                                               const float* __restrict__ bias, const float* __restrict__ res,
                                               float* __restrict__ outf, bf16* __restrict__ outb,
                                               bf16* __restrict__ vt, int M, int N, int K) {
    __shared__ __align__(16) short As[2][64 * 64];
    __shared__ __align__(16) short Bs[2][64 * 64];
    int tid = threadIdx.x;
    int wave = tid >> 6, lane = tid & 63;
    int frow = lane & 15, fquad = lane >> 4;
    int id = blockIdx.x;
    int m_low = id & 7;
    int s = id >> 3;
    int ni = s % NB;
    int mi = (s / NB) * 8 + m_low;
    int m0 = mi * 64, n0 = ni * 64;
    int wm = (wave & 1) * 32, wn = (wave >> 1) * 32;
    floatx4 acc[2][2] = {};
    const char* Ab = (const char*)A + (long)m0 * K * 2;
    const char* Bb = (const char*)Wt + (long)n0 * K * 2;
    long rs = (long)K * 2;
    int KT = K >> 6;
    stage_sw<64>(Ab, rs, 0, (char*)As[0], tid);
    stage_sw<64>(Bb, rs, 0, (char*)Bs[0], tid);
    for (int kt = 0; kt < KT; ++kt) {
        int cur = kt & 1;
        __syncthreads();
        if (kt + 1 < KT) {
            stage_sw<64>(Ab, rs, (kt + 1) * 128, (char*)As[1 - cur], tid);
            stage_sw<64>(Bb, rs, (kt + 1) * 128, (char*)Bs[1 - cur], tid);
        }
        const char* Ap = (const char*)As[cur];
        const char* Bp = (const char*)Bs[cur];
#pragma unroll
        for (int kh = 0; kh < 2; ++kh) {
            short8 af[2], bw[2];
#pragma unroll
            for (int i = 0; i < 2; ++i)
                af[i] = *(const short8*)(Ap + sw_off(wm + i * 16 + frow, kh * 4 + fquad));
#pragma unroll
            for (int j = 0; j < 2; ++j)
                bw[j] = *(const short8*)(Bp + sw_off(wn + j * 16 + frow, kh * 4 + fquad));
#pragma unroll
            for (int i = 0; i < 2; ++i)
#pragma unroll
                for (int j = 0; j < 2; ++j)
                    acc[i][j] = __builtin_amdgcn_mfma_f32_16x16x32_bf16(af[i], bw[j], acc[i][j], 0, 0, 0);
        }
    }
#pragma unroll
    for (int i = 0; i < 2; ++i) {
#pragma unroll
        for (int j = 0; j < 2; ++j) {
#pragma unroll
            for (int r = 0; r < 4; ++r) {
                int row = m0 + wm + i * 16 + fquad * 4 + r;
                int col = n0 + wn + j * 16 + frow;
                float v = acc[i][j][r];
                if (FLAGS & FB) v += bias[col];
                if (FLAGS & FG) v = gelu_f(v);
                if (FLAGS & FPE) v += pe_val(row & 511, col);
                if (FLAGS & FR) v += res[(long)row * N + col];
                if (VT) {
                    if (col < 512) {
                        outb[(long)row * 512 + col] = f2b(v);
                    } else {
                        int h = (col - 512) >> 5, d = col & 31;
                        int b = row >> 9, ss = row & 511;
                        vt[(long)((b * 8 + h) * 32 + d) * 512 + ss] = f2b(v);
                    }
                } else if (FLAGS & FO16) {
                    outb[(long)row * N + col] = f2b(v);
                } else {
                    outf[(long)row * N + col] = v;
                }
            }
        }
    }
}

// ---------------- fused flash attention (MFMA) ------------------------------
// qk (M,512) bf16: Q cols 0-255, K cols 256-511. Vt (B*H,32,512) bf16.
#define PSTR 136
__global__ __launch_bounds__(256) void fattn_kernel(const bf16* __restrict__ qk,
                                                    const bf16* __restrict__ Vt,
                                                    const float* __restrict__ bias_l,
                                                    bf16* __restrict__ ctx) {
    __shared__ __align__(16) short Ks[128 * 32];
    __shared__ __align__(16) short Vs[32 * 128];
    __shared__ __align__(16) short Ps[4 * 32 * PSTR];
    __shared__ float bias_s[640];
    int tid = threadIdx.x;
    int wave = tid >> 6, lane = tid & 63;
    int frow = lane & 15, fquad = lane >> 4;
    int bh = blockIdx.y;
    int b = bh >> 3, h = bh & 7;
    int i0 = blockIdx.x * 128;
    int wm = wave * 32;
    const float scale = 0.17677669529663687f;

    for (int t = tid; t < 639; t += 256) bias_s[t] = bias_l[(i0 + t) * 8 + h];

    short8 qf[2];
#pragma unroll
    for (int i = 0; i < 2; ++i)
        qf[i] = *(const short8*)((const short*)qk +
                 (long)((b << 9) + i0 + wm + i * 16 + frow) * 512 + h * 32 + fquad * 8);

    const char* gK = (const char*)qk + (long)b * 512 * 1024 + 512 + h * 64;
    const char* gV = (const char*)Vt + (long)bh * 32 * 1024;

    floatx4 acc_o[2][2] = {};
    float run_m[2][4], run_l[2][4];
#pragma unroll
    for (int i = 0; i < 2; ++i)
#pragma unroll
        for (int r = 0; r < 4; ++r) { run_m[i][r] = -1e30f; run_l[i][r] = 0.0f; }

    short* Pw = Ps + wave * 32 * PSTR;
    bf16* Pb = (bf16*)Pw;

    for (int j0 = 0; j0 < 512; j0 += 128) {
        {
            char* lpK = (char*)Ks + (tid & 192) * 16;
            char* lpV = (char*)Vs + (tid & 192) * 16;
#pragma unroll
            for (int r = 0; r < 2; ++r) {
                int off = r * 4096 + tid * 16;
                const char* gp = gK + (long)(j0 + (off >> 6)) * 1024 + (off & 63);
                __builtin_amdgcn_global_load_lds((const __attribute__((address_space(1))) void*)gp,
                                                 (__attribute__((address_space(3))) void*)(lpK + r * 4096), 16, 0, 0);
            }
#pragma unroll
            for (int r = 0; r < 2; ++r) {
                int off = r * 4096 + tid * 16;
                const char* gp = gV + (long)(off >> 8) * 1024 + j0 * 2 + (off & 255);
                __builtin_amdgcn_global_load_lds((const __attribute__((address_space(1))) void*)gp,
                                                 (__attribute__((address_space(3))) void*)(lpV + r * 4096), 16, 0, 0);
            }
        }
        __syncthreads();

        floatx4 accs[2][8] = {};
#pragma unroll
        for (int jt = 0; jt < 8; ++jt) {
            short8 bk = *(const short8*)(Ks + (jt * 16 + frow) * 32 + fquad * 8);
#pragma unroll
            for (int i = 0; i < 2; ++i)
                accs[i][jt] = __builtin_amdgcn_mfma_f32_16x16x32_bf16(qf[i], bk, accs[i][jt], 0, 0, 0);
        }
#pragma unroll
        for (int i = 0; i < 2; ++i) {
            int irel = wm + i * 16 + fquad * 4;
#pragma unroll
            for (int jt = 0; jt < 8; ++jt) {
                int jl = j0 + jt * 16 + frow;
#pragma unroll
                for (int r = 0; r < 4; ++r)
                    accs[i][jt][r] = accs[i][jt][r] * scale + bias_s[irel + r + 511 - jl];
            }
        }
#pragma unroll
        for (int i = 0; i < 2; ++i) {
#pragma unroll
            for (int r = 0; r < 4; ++r) {
                float m = -1e30f;
#pragma unroll
                for (int jt = 0; jt < 8; ++jt) m = fmaxf(m, accs[i][jt][r]);
                m = fmaxf(m, __shfl_xor(m, 1));
                m = fmaxf(m, __shfl_xor(m, 2));
                m = fmaxf(m, __shfl_xor(m, 4));
                m = fmaxf(m, __shfl_xor(m, 8));
                float nm = fmaxf(run_m[i][r], m);
                float al = __expf(run_m[i][r] - nm);
                run_m[i][r] = nm;
                float ts = 0.0f;
#pragma unroll
                for (int jt = 0; jt < 8; ++jt) {
                    float p = __expf(accs[i][jt][r] - nm);
                    accs[i][jt][r] = p;
                    ts += p;
                }
                ts += __shfl_xor(ts, 1);
                ts += __shfl_xor(ts, 2);
                ts += __shfl_xor(ts, 4);
                ts += __shfl_xor(ts, 8);
                run_l[i][r] = run_l[i][r] * al + ts;
                acc_o[i][0][r] *= al;
                acc_o[i][1][r] *= al;
            }
        }
#pragma unroll
        for (int i = 0; i < 2; ++i)
#pragma unroll
            for (int jt = 0; jt < 8; ++jt)
#pragma unroll
                for (int r = 0; r < 4; ++r)
                    Pb[(i * 16 + fquad * 4 + r) * PSTR + jt * 16 + frow] = f2b(accs[i][jt][r]);
#pragma unroll
        for (int ks = 0; ks < 4; ++ks) {
            short8 ap[2], bv[2];
#pragma unroll
            for (int i = 0; i < 2; ++i)
                ap[i] = *(const short8*)(Pw + (i * 16 + frow) * PSTR + ks * 32 + fquad * 8);
#pragma unroll
            for (int dt = 0; dt < 2; ++dt)
                bv[dt] = *(const short8*)(Vs + (dt * 16 + frow) * 128 + ks * 32 + fquad * 8);
#pragma unroll
            for (int i = 0; i < 2; ++i)
#pragma unroll
                for (int dt = 0; dt < 2; ++dt)
                    acc_o[i][dt] = __builtin_amdgcn_mfma_f32_16x16x32_bf16(ap[i], bv[dt], acc_o[i][dt], 0, 0, 0);
        }
        __syncthreads();
    }

#pragma unroll
    for (int i = 0; i < 2; ++i) {
#pragma unroll
        for (int r = 0; r < 4; ++r) {
            float inv = 1.0f / run_l[i][r];
            int row = i0 + wm + i * 16 + fquad * 4 + r;
#pragma unroll
            for (int dt = 0; dt < 2; ++dt) {
                int d = dt * 16 + frow;
                ctx[(long)((b << 9) + row) * 256 + h * 32 + d] = f2b(acc_o[i][dt][r] * inv);
            }
        }
    }
}

extern "C" void kernel_launch(void* const* d_in, const int* in_sizes, int n_in,
                              void* d_out, int out_size, void* d_ws, size_t ws_size,
                              hipStream_t stream) {
    const float* x        = (const float*)d_in[0];
    const float* conv1_w  = (const float*)d_in[1];
    const float* conv1_b  = (const float*)d_in[2];
    const float* bn1_g    = (const float*)d_in[3];
    const float* bn1_b    = (const float*)d_in[4];
    const float* conv2_w  = (const float*)d_in[5];
    const float* conv2_b  = (const float*)d_in[6];
    const float* bn2_g    = (const float*)d_in[7];
    const float* bn2_b    = (const float*)d_in[8];
    const float* ln1_g    = (const float*)d_in[9];
    const float* ln1_b    = (const float*)d_in[10];
    const float* wq       = (const float*)d_in[11];
    const float* wk       = (const float*)d_in[12];
    const float* wv       = (const float*)d_in[13];
    const float* wo       = (const float*)d_in[14];
    const float* bo       = (const float*)d_in[15];
    const float* bias_tab = (const float*)d_in[16];
    const float* ln2_g    = (const float*)d_in[17];
    const float* ln2_b    = (const float*)d_in[18];
    const float* w1       = (const float*)d_in[19];
    const float* b1       = (const float*)d_in[20];
    const float* w2       = (const float*)d_in[21];
    const float* b2       = (const float*)d_in[22];
    const float* fn_g     = (const float*)d_in[23];
    const float* fn_b     = (const float*)d_in[24];
    (void)in_sizes; (void)n_in; (void)out_size; (void)ws_size;

    const int M = B_ * S_;  // 8192
    char* wsb = (char*)d_ws;
    float* t    = (float*)wsb;                          // [0, 8M)
    bf16* qk    = (bf16*)(wsb + (8u << 20));            // [8M, 16M)  Q|K (M,512)
    bf16* h1    = (bf16*)(wsb + (8u << 20));            // alias (4 MB, dead before qk)
    char* reg2  = wsb + (16u << 20);                    // [16M, 36M)
    bf16* Vt    = (bf16*)reg2;                          // 8 MB  (qkv-gemm -> fattn)
    bf16* ff1   = (bf16*)reg2;                          // 16 MB (ff1-gemm -> ff2-gemm)
    bf16* col1  = (bf16*)reg2;                          // alias (tokenizer, 4 MB)
    bf16* col2  = (bf16*)reg2;                          // alias (tokenizer, 20 MB)
    bf16* xnctx = (bf16*)(reg2 + (20u << 20));          // 4 MB (xn and ctx)
    bf16* wqkvT = (bf16*)(wsb + (40u << 20));           // L*768*256
    bf16* woT   = wqkvT + (long)L_ * 768 * 256;         // L*256*256
    bf16* w1T   = woT + (long)L_ * 256 * 256;           // L*1024*256
    bf16* w2T   = w1T + (long)L_ * 1024 * 256;          // L*256*1024
    bf16* c1w   = w2T + (long)L_ * 256 * 1024;          // 256*256 (padded K)
    bf16* c2w   = c1w + 256 * 256;                      // 256*1280
    float* sh1  = (float*)(c2w + 256 * 1280);           // 256
    float* sh2  = sh1 + 256;                            // 256

    // ---- weight prep (single launch) ----
    prep_kernel<<<3104, 256, 0, stream>>>(wq, wk, wv, wo, w1, w2,
                                          wqkvT, woT, w1T, w2T,
                                          conv1_w, conv1_b, bn1_g, bn1_b,
                                          conv2_w, conv2_b, bn2_g, bn2_b,
                                          c1w, c2w, sh1, sh2);

    // ---- tokenizer ----
    im2col1_kernel<<<dim3(8, B_), 256, 0, stream>>>(x, col1);
    gemm_sw<4, FB | FG | FO16, false><<<512, 256, 0, stream>>>(
        col1, c1w, sh1, nullptr, nullptr, h1, nullptr, M, 256, 256);
    im2col2_kernel<<<dim3(5, B_), 256, 0, stream>>>(h1, col2);
    gemm_sw<4, FB | FG | FPE, false><<<512, 256, 0, stream>>>(
        col2, c2w, sh2, nullptr, t, nullptr, nullptr, M, 256, 1280);

    // ---- transformer layers ----
    for (int l = 0; l < L_; ++l) {
        ln_kernel<true><<<M, 256, 0, stream>>>(t, ln1_g + l * D_, ln1_b + l * D_, nullptr, xnctx);
        gemm_sw<12, FO16, true><<<1536, 256, 0, stream>>>(
            xnctx, wqkvT + (long)l * 768 * 256, nullptr, nullptr, nullptr, qk, Vt, M, 768, 256);
        fattn_kernel<<<dim3(4, B_ * H_), 256, 0, stream>>>(
            qk, Vt, bias_tab + (long)l * (2 * S_ - 1) * H_, xnctx);
        gemm_sw<4, FB | FR, false><<<512, 256, 0, stream>>>(
            xnctx, woT + (long)l * 65536, bo + l * D_, t, t, nullptr, nullptr, M, 256, 256);
        ln_kernel<true><<<M, 256, 0, stream>>>(t, ln2_g + l * D_, ln2_b + l * D_, nullptr, xnctx);
        gemm_sw<16, FB | FG | FO16, false><<<2048, 256, 0, stream>>>(
            xnctx, w1T + (long)l * 262144, b1 + l * FF_, nullptr, nullptr, ff1, nullptr, M, 1024, 256);
        gemm_sw<4, FB | FR, false><<<512, 256, 0, stream>>>(
            ff1, w2T + (long)l * 262144, b2 + l * D_, t, t, nullptr, nullptr, M, 256, 1024);
    }
    ln_kernel<false><<<M, 256, 0, stream>>>(t, fn_g, fn_b, (float*)d_out, nullptr);
}